// Round 7
// baseline (602.684 us; speedup 1.0000x reference)
//
#include <hip/hip_runtime.h>
#include <hip/hip_bf16.h>

// ---------------------------------------------------------------------------
// CapsuleNet forward. Round 17 = Round 15/16 resubmit (container-acquire
// flake bursts; R11/R12->R13 precedent: identical source passed on 3rd try).
//  Identity: b_ij after iter r = u_hat . (v_0+...+v_r) = u_hat . Vsum.
//  So routing needs only Vsum[b][160]; u_hat (755 MFLOP) is recomputed on the
//  fly from caps (9.4 MB) + W (2.95 MB bf16) inside route_fused. This deletes
//  uhat_t (94 MB write), 3x routeAB (~470 MB of uT re-reads), and bbuf.
//  route_fused: block = 64 i x 8 b. LDS: caps tile 16K + W-group dbuf 32K +
//  Vsum 5K = 53 KB. W tile layout [jdl][il][k] -> ds_read_b128 bank group =
//  lane mod 8 (conflict-free). Online softmax (running m,Z; no runtime-
//  indexed arrays -> no scratch). Sweep2 keeps u[16] in regs, butterfly-
//  reduces over the 64-lane i dim, lane<16 stores 64B-coalesced partials.
//  vsqF folds 18 chunk partials + bias + squash, maintains Vsum.
//  conv front-end (conv1/arepack/conv2/squash4) is Round-10-exact.
//
// Workspace (bytes):
//   ht    @ 0           : 52,428,800
//   A2    @ 52,428,800  : 10,616,832 -> 63,045,632
//   caps4 @ 63,045,632  : 37,748,736 -> 100,794,368
//   caps  @ 100,794,368 : 9,437,184  -> 110,231,552
//   Wrb2  @ 110,231,552 : 2,949,120  -> 113,180,672  ([18][10][16][64][8] bf16)
//   spart @ 113,180,672 : 2,949,120  -> 116,129,792  ([18][256][160] f32)
//   vsum  @ 116,129,792 : 163,840    -> 116,293,632  ([256][160] f32)
// ---------------------------------------------------------------------------

typedef __attribute__((ext_vector_type(8))) short short8;
typedef __attribute__((ext_vector_type(4))) float float4v;

__device__ inline float bfu(ushort v){ return __uint_as_float((unsigned)v << 16); }

// conv1: x[256,1,28,28] * w[256,1,9,9] -> h_t[b][pos 400][c 256] bf16
__global__ __launch_bounds__(640) void conv1_kernel(const float* __restrict__ x,
    const float* __restrict__ w, const float* __restrict__ bias,
    __hip_bfloat16* __restrict__ ht){
  __shared__ float img[784];
  __shared__ float wsv[32 * 81];
  __shared__ ushort tile[400 * 33];
  int b = blockIdx.x;
  int og = blockIdx.y;
  int t = threadIdx.x;
  const float* xb = x + (size_t)b * 784;
  for (int idx = t; idx < 784; idx += 640) img[idx] = xb[idx];
  for (int idx = t; idx < 2592; idx += 640) wsv[idx] = w[(size_t)og * 2592 + idx];
  __syncthreads();
  int o_l = t / 20;
  int y   = t - o_l * 20;
  float acc[20];
  #pragma unroll
  for (int i = 0; i < 20; i++) acc[i] = 0.f;
  #pragma unroll
  for (int r = 0; r < 9; r++){
    float row[28];
    const float4* rp = (const float4*)&img[(y + r) * 28];
    #pragma unroll
    for (int q = 0; q < 7; q++){
      float4 v4 = rp[q];
      row[4*q+0]=v4.x; row[4*q+1]=v4.y; row[4*q+2]=v4.z; row[4*q+3]=v4.w;
    }
    #pragma unroll
    for (int s = 0; s < 9; s++){
      float wv = wsv[o_l * 81 + r * 9 + s];
      #pragma unroll
      for (int xx = 0; xx < 20; xx++)
        acc[xx] = fmaf(wv, row[xx + s], acc[xx]);
    }
  }
  float bv = bias[og * 32 + o_l];
  #pragma unroll
  for (int xx = 0; xx < 20; xx++){
    __hip_bfloat16 hv = __float2bfloat16(acc[xx] + bv);
    tile[(y * 20 + xx) * 33 + o_l] = *(ushort*)&hv;
  }
  __syncthreads();
  __hip_bfloat16* hb = ht + (size_t)b * 102400 + og * 32;
  for (int idx = t; idx < 6400; idx += 640){
    int pos = idx >> 4, op = idx & 15;
    unsigned v = (unsigned)tile[pos * 33 + op * 2]
               | ((unsigned)tile[pos * 33 + op * 2 + 1] << 16);
    *(unsigned*)(hb + (size_t)pos * 256 + op * 2) = v;
  }
}

// repack conv2 weights (wave-tiled)
__global__ __launch_bounds__(256) void arepack_kernel(const float* __restrict__ w2,
    ushort* __restrict__ A2s){
  __shared__ float wbuf[64 * 81];
  int o = blockIdx.x;
  int t = threadIdx.x;
  int ow = o >> 6, fo = (o >> 4) & 3, l15 = o & 15;
  size_t obase8 = (size_t)ow * 165888 + (size_t)fo * 64 + (size_t)l15 * 4;
  for (int c0 = 0; c0 < 256; c0 += 64){
    __syncthreads();
    for (int idx = t; idx < 5184; idx += 256)
      wbuf[idx] = w2[(size_t)o * 20736 + (size_t)c0 * 81 + idx];
    __syncthreads();
    for (int idx = t; idx < 2592; idx += 256){
      int rs = idx >> 5;
      int cp = (idx & 31) * 2;
      int cg = c0 + cp;
      int ct = cg >> 5, quad = (cg >> 3) & 3, e = cg & 7;
      __hip_bfloat16 b0 = __float2bfloat16(wbuf[cp * 81 + rs]);
      __hip_bfloat16 b1 = __float2bfloat16(wbuf[(cp + 1) * 81 + rs]);
      unsigned pack = (unsigned)*(ushort*)&b0 | ((unsigned)*(ushort*)&b1 << 16);
      size_t si = (obase8 + (size_t)ct * 256 + (size_t)rs * 2048 + quad) * 8 + e;
      *(unsigned*)(A2s + si) = pack;
    }
  }
}

// W [1152][10][16][8] f32 -> Wrb2 [ic 18][j 10][d 16][il 64][k 8] bf16
__global__ __launch_bounds__(256) void wrepack2_kernel(const float* __restrict__ W,
    ushort* __restrict__ Wrb2){
  int ic = blockIdx.x;   // 0..17
  int j  = blockIdx.y;   // 0..9
  int t = threadIdx.x;
  for (int it = t; it < 1024; it += 256){
    int d = it >> 6, il = it & 63;
    const float* src = W + (size_t)(ic*64 + il)*1280 + j*128 + d*8;
    float4 a = *(const float4*)src;
    float4 b = *(const float4*)(src + 4);
    float vals[8] = {a.x,a.y,a.z,a.w,b.x,b.y,b.z,b.w};
    unsigned p[4];
    #pragma unroll
    for (int e = 0; e < 4; e++){
      __hip_bfloat16 h0 = __float2bfloat16(vals[2*e]);
      __hip_bfloat16 h1 = __float2bfloat16(vals[2*e+1]);
      p[e] = (unsigned)*(ushort*)&h0 | ((unsigned)*(ushort*)&h1 << 16);
    }
    uint4 pv = {p[0], p[1], p[2], p[3]};
    *(uint4*)(Wrb2 + ((((size_t)ic*10 + j)*16 + d)*64 + il)*8) = pv;
  }
}

// conv2 implicit GEMM, 2 images/block (R6-verified, Round-10-exact)
__global__ __launch_bounds__(256, 2) void conv2_mfma_kernel(
    const __hip_bfloat16* __restrict__ ht, const short8* __restrict__ A2,
    float* __restrict__ caps4){
  __shared__ ushort img[2][400 * 40];
  int bx  = blockIdx.x;
  int xcd = bx & 7;
  int kq  = xcd >> 1;
  int p   = ((bx >> 3) << 1) | (xcd & 1);
  int b0  = p * 2;
  int t = threadIdx.x;
  int lane = t & 63;
  int wid  = t >> 6;
  int l15  = lane & 15;
  int quad = lane >> 4;

  int bn[3], slc[3];
  #pragma unroll
  for (int fn = 0; fn < 3; fn++){
    int n = fn * 16 + l15;
    int y = n / 6, xx = n - y * 6;
    if (n >= 36){ y = 0; xx = 0; }
    bn[fn]  = 40 * y + 2 * xx;
    slc[fn] = (quad + 4 * y) % 5;
  }
  const short8* i0p = (const short8*)&img[0][0];
  const short8* i1p = (const short8*)&img[1][0];

  float4v acc[4][6];
  #pragma unroll
  for (int fo = 0; fo < 4; fo++)
    #pragma unroll
    for (int fn = 0; fn < 6; fn++)
      acc[fo][fn] = (float4v){0.f, 0.f, 0.f, 0.f};

  for (int ci = 0; ci < 2; ci++){
    int ct = kq * 2 + ci;
    __syncthreads();
    #pragma unroll
    for (int im = 0; im < 2; im++){
      const __hip_bfloat16* hb = ht + (size_t)(b0 + im) * 102400;
      for (int idx = t; idx < 1600; idx += 256){
        int pp = idx >> 2, q = idx & 3;
        int sl = (q + 2 * (pp / 20)) % 5;
        uint4 v = *(const uint4*)(hb + (size_t)pp * 256 + ct * 32 + q * 8);
        *(uint4*)&img[im][pp * 40 + sl * 8] = v;
      }
    }
    __syncthreads();

    const short8* ap = A2 + ((size_t)wid * 648 + ct) * 256 + l15 * 4 + quad;

    short8 aF[2][4], bF[2][6];
    #pragma unroll
    for (int fo = 0; fo < 4; fo++) aF[0][fo] = ap[fo * 64];
    #pragma unroll
    for (int fn = 0; fn < 6; fn++){
      int f3 = (fn < 3) ? fn : fn - 3;
      const short8* ib = (fn < 3) ? i0p : i1p;
      bF[0][fn] = ib[bn[f3] * 5 + slc[f3]];
    }

    int rn = 0, sn = 0, r2m = 0;
    #pragma unroll 2
    for (int rs = 0; rs < 81; rs++){
      int cur = rs & 1, nxt = cur ^ 1;
      sn++;
      if (sn == 9){ sn = 0; rn++; r2m += 2; if (r2m >= 5) r2m -= 5; }
      int nrs = (rs < 80) ? rs + 1 : 80;
      int roff = rn * 20 + sn;
      const short8* apn = ap + (size_t)nrs * 2048;
      #pragma unroll
      for (int fo = 0; fo < 4; fo++) aF[nxt][fo] = apn[fo * 64];
      #pragma unroll
      for (int fn = 0; fn < 6; fn++){
        int f3 = (fn < 3) ? fn : fn - 3;
        const short8* ib = (fn < 3) ? i0p : i1p;
        int sl = slc[f3] + r2m; if (sl >= 5) sl -= 5;
        bF[nxt][fn] = ib[(bn[f3] + roff) * 5 + sl];
      }
      #pragma unroll
      for (int fo = 0; fo < 4; fo++)
        #pragma unroll
        for (int fn = 0; fn < 6; fn++)
          acc[fo][fn] = __builtin_amdgcn_mfma_f32_16x16x32_bf16(aF[cur][fo], bF[cur][fn], acc[fo][fn], 0, 0, 0);
    }
  }

  #pragma unroll
  for (int fn = 0; fn < 6; fn++){
    int im = (fn < 3) ? 0 : 1;
    int f3 = (fn < 3) ? fn : fn - 3;
    int pos = f3 * 16 + l15;
    if (pos < 36){
      float* cb = caps4 + ((size_t)kq * 256 + b0 + im) * 9216;
      #pragma unroll
      for (int fo = 0; fo < 4; fo++){
        int ob = wid * 64 + fo * 16 + quad * 4;
        #pragma unroll
        for (int rr = 0; rr < 4; rr++)
          cb[(size_t)(ob + rr) * 36 + pos] = acc[fo][fn][rr];
      }
    }
  }
}

// sum 4 kq-partials + bias, squash -> caps [b][i][8] fp32
__global__ __launch_bounds__(256) void squash4_kernel(const float* __restrict__ caps4,
    const float* __restrict__ bias, float* __restrict__ caps){
  size_t cid = (size_t)blockIdx.x * 256 + threadIdx.x;
  size_t base = cid * 8;
  const size_t STR = 2359296;
  float4 a0 = *(const float4*)(caps4 + base);
  float4 a1 = *(const float4*)(caps4 + base + 4);
  #pragma unroll
  for (int k = 1; k < 4; k++){
    float4 q0 = *(const float4*)(caps4 + k * STR + base);
    float4 q1 = *(const float4*)(caps4 + k * STR + base + 4);
    a0.x+=q0.x; a0.y+=q0.y; a0.z+=q0.z; a0.w+=q0.w;
    a1.x+=q1.x; a1.y+=q1.y; a1.z+=q1.z; a1.w+=q1.w;
  }
  int off = (int)(base % 9216);
  float v[8] = {a0.x,a0.y,a0.z,a0.w,a1.x,a1.y,a1.z,a1.w};
  #pragma unroll
  for (int e = 0; e < 8; e++) v[e] += bias[(off + e) / 36];
  float msq = 0.f;
  #pragma unroll
  for (int e = 0; e < 8; e++) msq += v[e]*v[e];
  float scale = sqrtf(msq) / (1.f + msq);
  float* cp = caps + base;
  #pragma unroll
  for (int e = 0; e < 8; e++) cp[e] = v[e]*scale;
}

// Fused routing iteration. Block: 64 i (lane) x 8 b (2 per wave).
// mode 0: c = 0.1 (skip dot sweep). mode 1: c = softmax(u_hat . Vsum).
// Writes spart[ic][b][160] = sum over this block's 64 i of c_ij * u_hat.
__global__ __launch_bounds__(256) void route_fused_kernel(
    const float* __restrict__ caps, const ushort* __restrict__ Wrb2,
    const float* __restrict__ vsum, float* __restrict__ spart, int mode){
  __shared__ float cl[8 * 8 * 64];      // [k][bb][il] 16 KB
  __shared__ ushort Wt[2][16 * 64 * 8]; // [jdl][il][k] 16 KB x2
  __shared__ float vsl[8 * 160];        // 5 KB
  int ic = blockIdx.x;        // 0..17
  int b0 = blockIdx.y * 8;    // 0..248
  int t = threadIdx.x, lane = t & 63, wid = t >> 6;
  int bbA = wid * 2, bbB = bbA + 1;

  for (int f = t; f < 1024; f += 256){
    int base = f * 4; int bb = base >> 9; int r = base & 511;
    int il = r >> 3; int k = r & 7;
    float4 v = *(const float4*)(caps + ((size_t)(b0+bb)*1152 + ic*64 + il)*8 + k);
    cl[((k+0)*8+bb)*64+il] = v.x;
    cl[((k+1)*8+bb)*64+il] = v.y;
    cl[((k+2)*8+bb)*64+il] = v.z;
    cl[((k+3)*8+bb)*64+il] = v.w;
  }
  if (mode)
    for (int f = t; f < 1280; f += 256) vsl[f] = vsum[(size_t)b0 * 160 + f];
  __syncthreads();

  float clrA[8], clrB[8];
  #pragma unroll
  for (int k = 0; k < 8; k++){
    clrA[k] = cl[(k*8 + bbA)*64 + lane];
    clrB[k] = cl[(k*8 + bbB)*64 + lane];
  }

  const uint4* wsrc = (const uint4*)(Wrb2 + (size_t)ic * 81920);
  uint4* wd0 = (uint4*)&Wt[0][0];
  uint4* wd1 = (uint4*)&Wt[1][0];

  float m0 = -1e30f, m1 = -1e30f, z0 = 0.f, z1 = 0.f;

  if (mode){
    // ---- sweep 1: online softmax stats over d_j = sum_jd u.Vsum ----
    #pragma unroll
    for (int u = 0; u < 4; u++) wd0[t + 256*u] = wsrc[t + 256*u];
    __syncthreads();
    for (int jg = 0; jg < 10; jg++){
      if (jg < 9){
        uint4* wd = (jg & 1) ? wd0 : wd1;
        const uint4* wsp = wsrc + (size_t)(jg+1) * 1024;
        #pragma unroll
        for (int u = 0; u < 4; u++) wd[t + 256*u] = wsp[t + 256*u];
      }
      const ushort* wb = (jg & 1) ? &Wt[1][0] : &Wt[0][0];
      float da = 0.f, db = 0.f;
      #pragma unroll
      for (int jdl = 0; jdl < 16; jdl++){
        uint4 wv = *(const uint4*)&wb[((size_t)jdl*64 + lane)*8];
        float wk[8];
        wk[0]=bfu((ushort)(wv.x&0xffffu)); wk[1]=bfu((ushort)(wv.x>>16));
        wk[2]=bfu((ushort)(wv.y&0xffffu)); wk[3]=bfu((ushort)(wv.y>>16));
        wk[4]=bfu((ushort)(wv.z&0xffffu)); wk[5]=bfu((ushort)(wv.z>>16));
        wk[6]=bfu((ushort)(wv.w&0xffffu)); wk[7]=bfu((ushort)(wv.w>>16));
        float u0 = 0.f, u1 = 0.f;
        #pragma unroll
        for (int k = 0; k < 8; k++){
          u0 = fmaf(wk[k], clrA[k], u0);
          u1 = fmaf(wk[k], clrB[k], u1);
        }
        int jd = jg*16 + jdl;
        da = fmaf(u0, vsl[bbA*160 + jd], da);
        db = fmaf(u1, vsl[bbB*160 + jd], db);
      }
      // online max/sum update (j == jg)
      float n0 = fmaxf(m0, da);
      z0 = z0 * __expf(m0 - n0) + __expf(da - n0);
      m0 = n0;
      float n1 = fmaxf(m1, db);
      z1 = z1 * __expf(m1 - n1) + __expf(db - n1);
      m1 = n1;
      __syncthreads();
    }
  }
  float iz0 = mode ? 1.f / z0 : 0.f;
  float iz1 = mode ? 1.f / z1 : 0.f;

  // ---- sweep 2: s_j partials ----
  #pragma unroll
  for (int u = 0; u < 4; u++) wd0[t + 256*u] = wsrc[t + 256*u];
  __syncthreads();
  for (int jg = 0; jg < 10; jg++){
    if (jg < 9){
      uint4* wd = (jg & 1) ? wd0 : wd1;
      const uint4* wsp = wsrc + (size_t)(jg+1) * 1024;
      #pragma unroll
      for (int u = 0; u < 4; u++) wd[t + 256*u] = wsp[t + 256*u];
    }
    const ushort* wb = (jg & 1) ? &Wt[1][0] : &Wt[0][0];
    float u0[16], u1[16];
    float da = 0.f, db = 0.f;
    #pragma unroll
    for (int jdl = 0; jdl < 16; jdl++){
      uint4 wv = *(const uint4*)&wb[((size_t)jdl*64 + lane)*8];
      float wk[8];
      wk[0]=bfu((ushort)(wv.x&0xffffu)); wk[1]=bfu((ushort)(wv.x>>16));
      wk[2]=bfu((ushort)(wv.y&0xffffu)); wk[3]=bfu((ushort)(wv.y>>16));
      wk[4]=bfu((ushort)(wv.z&0xffffu)); wk[5]=bfu((ushort)(wv.z>>16));
      wk[6]=bfu((ushort)(wv.w&0xffffu)); wk[7]=bfu((ushort)(wv.w>>16));
      float a0 = 0.f, a1 = 0.f;
      #pragma unroll
      for (int k = 0; k < 8; k++){
        a0 = fmaf(wk[k], clrA[k], a0);
        a1 = fmaf(wk[k], clrB[k], a1);
      }
      u0[jdl] = a0; u1[jdl] = a1;
      if (mode){
        int jd = jg*16 + jdl;
        da = fmaf(a0, vsl[bbA*160 + jd], da);
        db = fmaf(a1, vsl[bbB*160 + jd], db);
      }
    }
    float cv0 = mode ? __expf(da - m0) * iz0 : 0.1f;
    float cv1 = mode ? __expf(db - m1) * iz1 : 0.1f;
    float r0 = 0.f, r1 = 0.f;
    #pragma unroll
    for (int jdl = 0; jdl < 16; jdl++){
      float t0 = cv0 * u0[jdl];
      float t1 = cv1 * u1[jdl];
      t0 += __shfl_xor(t0, 32); t1 += __shfl_xor(t1, 32);
      t0 += __shfl_xor(t0, 16); t1 += __shfl_xor(t1, 16);
      t0 += __shfl_xor(t0, 8);  t1 += __shfl_xor(t1, 8);
      t0 += __shfl_xor(t0, 4);  t1 += __shfl_xor(t1, 4);
      t0 += __shfl_xor(t0, 2);  t1 += __shfl_xor(t1, 2);
      t0 += __shfl_xor(t0, 1);  t1 += __shfl_xor(t1, 1);
      if (lane == jdl){ r0 = t0; r1 = t1; }
    }
    if (lane < 16){
      spart[((size_t)ic*256 + b0 + bbA)*160 + jg*16 + lane] = r0;
      spart[((size_t)ic*256 + b0 + bbB)*160 + jg*16 + lane] = r1;
    }
    __syncthreads();
  }
}

// sum 18 chunk partials + bias, squash over 16-groups.
// mode 0: vsum = v; 1: vsum += v; 2: out = v (final).
__global__ __launch_bounds__(160) void vsqF_kernel(const float* __restrict__ spart,
    const float* __restrict__ dcb, float* __restrict__ vsum,
    float* __restrict__ out, int mode){
  int b = blockIdx.x;
  int t = threadIdx.x;   // 0..159
  float s = dcb[t];
  #pragma unroll
  for (int c = 0; c < 18; c++) s += spart[((size_t)c * 256 + b) * 160 + t];
  float msq = s * s;
  msq += __shfl_xor(msq, 1, 16);
  msq += __shfl_xor(msq, 2, 16);
  msq += __shfl_xor(msq, 4, 16);
  msq += __shfl_xor(msq, 8, 16);
  float scale = sqrtf(msq) / (1.f + msq);
  float v = s * scale;
  if (mode == 2)      out[b * 160 + t] = v;
  else if (mode == 1) vsum[b * 160 + t] += v;
  else                vsum[b * 160 + t] = v;
}

extern "C" void kernel_launch(void* const* d_in, const int* in_sizes, int n_in,
                              void* d_out, int out_size, void* d_ws, size_t ws_size,
                              hipStream_t stream){
  (void)in_sizes; (void)n_in; (void)out_size; (void)ws_size;
  const float* x   = (const float*)d_in[0];
  const float* w1  = (const float*)d_in[1];
  const float* b1  = (const float*)d_in[2];
  const float* w2  = (const float*)d_in[3];
  const float* b2  = (const float*)d_in[4];
  const float* W   = (const float*)d_in[5];
  const float* dcb = (const float*)d_in[6];
  float* out = (float*)d_out;

  char* ws = (char*)d_ws;
  __hip_bfloat16* ht = (__hip_bfloat16*)(ws);
  ushort* A2s  = (ushort*)(ws + 52428800);
  float* caps4 = (float*)(ws + 63045632);
  float* caps  = (float*)(ws + 100794368);
  ushort* Wrb2 = (ushort*)(ws + 110231552);
  float* spart = (float*)(ws + 113180672);
  float* vsum  = (float*)(ws + 116129792);

  conv1_kernel<<<dim3(256, 8), 640, 0, stream>>>(x, w1, b1, ht);
  arepack_kernel<<<256, 256, 0, stream>>>(w2, A2s);
  wrepack2_kernel<<<dim3(18, 10), 256, 0, stream>>>(W, Wrb2);
  conv2_mfma_kernel<<<512, 256, 0, stream>>>(ht, (const short8*)A2s, caps4);
  squash4_kernel<<<1152, 256, 0, stream>>>(caps4, b2, caps);

  route_fused_kernel<<<dim3(18, 32), 256, 0, stream>>>(caps, Wrb2, vsum, spart, 0);
  vsqF_kernel<<<256, 160, 0, stream>>>(spart, dcb, vsum, out, 0);
  route_fused_kernel<<<dim3(18, 32), 256, 0, stream>>>(caps, Wrb2, vsum, spart, 1);
  vsqF_kernel<<<256, 160, 0, stream>>>(spart, dcb, vsum, out, 1);
  route_fused_kernel<<<dim3(18, 32), 256, 0, stream>>>(caps, Wrb2, vsum, spart, 2);
  vsqF_kernel<<<256, 160, 0, stream>>>(spart, dcb, vsum, out, 2);
}